// Round 4
// baseline (719.172 us; speedup 1.0000x reference)
//
#include <hip/hip_runtime.h>
#include <hip/hip_cooperative_groups.h>
#include <stdint.h>

namespace cg = cooperative_groups;

typedef unsigned short u16;
typedef __attribute__((ext_vector_type(8))) short short8;   // 8 bf16 (4 VGPRs) — MFMA A/B frag
typedef __attribute__((ext_vector_type(4))) float float4v;  // MFMA C/D frag

__device__ __forceinline__ u16 f2bf(float f) {
    union { float f; uint32_t u; } v; v.f = f;
    uint32_t r = v.u + 0x7fffu + ((v.u >> 16) & 1u);  // RNE
    return (u16)(r >> 16);
}

__device__ __forceinline__ void gload16(const u16* g, u16* l) {
    __builtin_amdgcn_global_load_lds(
        (const __attribute__((address_space(1))) void*)g,
        (__attribute__((address_space(3))) void*)l, 16, 0, 0);
}

struct Params {
    const float *x, *wts, *W0, *b0, *a0, *W1, *b1, *a1, *W2, *b2, *a2;
    u16 *xbf, *act1, *act2, *W0t, *W1t, *W2t;
    float *mb;
    float *out;
};

// ---------------- prep (device fn, 512 blocks x 512 thr) ----------------
// x->bf16; W [E=8,K,N] f32 -> Wt [N,K] bf16 merged; bias merge (2560).
__device__ void prep_phase(const Params& p, int bid, int tid, float (*tile)[33]) {
    for (int i = (bid * 512 + tid) * 4; i < 8192 * 512; i += 512 * 512 * 4) {
        float4 v = *(const float4*)(p.x + i);
        union { u16 s[4]; uint64_t q; } o;
        o.s[0] = f2bf(v.x); o.s[1] = f2bf(v.y); o.s[2] = f2bf(v.z); o.s[3] = f2bf(v.w);
        *(uint64_t*)(p.xbf + i) = o.q;
    }

    float wnv[8]; float ssum = 0.f;
    #pragma unroll
    for (int e = 0; e < 8; ++e) { wnv[e] = p.wts[e]; ssum += wnv[e]; }
    const float inv = 1.0f / ssum;

    // 2048 32x32 transpose units, 4 per block
    for (int u = bid; u < 2048; u += 512) {
        const float* W; u16* Wt; int K, N, lb;
        if (u < 512)       { W = p.W0; Wt = p.W0t; K = 512;  N = 1024; lb = u; }
        else if (u < 1536) { W = p.W1; Wt = p.W1t; K = 1024; N = 1024; lb = u - 512; }
        else               { W = p.W2; Wt = p.W2t; K = 1024; N = 512;  lb = u - 1536; }
        const int nt = N >> 5;
        const int o0 = (lb % nt) * 32, i0 = (lb / nt) * 32;
        const int tx = tid & 31, ty = tid >> 5;          // ty 0..15
        __syncthreads();                                  // LDS reuse guard
        #pragma unroll
        for (int s4 = 0; s4 < 2; ++s4) {
            int il = ty + s4 * 16;
            float acc = 0.f;
            #pragma unroll
            for (int e = 0; e < 8; ++e)
                acc += wnv[e] * W[(size_t)e * K * N + (size_t)(i0 + il) * N + o0 + tx];
            tile[il][tx] = acc * inv;
        }
        __syncthreads();
        #pragma unroll
        for (int s4 = 0; s4 < 2; ++s4) {
            int ol = ty + s4 * 16;
            Wt[(size_t)(o0 + ol) * K + i0 + tx] = f2bf(tile[tx][ol]);
        }
    }

    if (bid < 5) {
        int t = bid * 512 + tid;
        if (t < 2560) {
            const float* bp; int o, stride;
            if (t < 1024)      { bp = p.b0; o = t;        stride = 1024; }
            else if (t < 2048) { bp = p.b1; o = t - 1024; stride = 1024; }
            else               { bp = p.b2; o = t - 2048; stride = 512;  }
            float acc = 0.f;
            #pragma unroll
            for (int e = 0; e < 8; ++e) acc += wnv[e] * bp[e * stride + o];
            p.mb[t] = acc * inv;
        }
    }
}

// ------------- GEMM tile: 128(M) x 128(N), BK=64, 512 thr = 8 waves (2M x 4N) -------------
// A [8192,K] bf16 row-major, Bt [N,K] bf16. XOR chunk swizzle applied on the GLOBAL
// source address at staging (LDS side lane-contiguous per global_load_lds constraint),
// mirrored on ds_read addresses -> fragment reads 2-way (free, m136).
template <bool OUT_F32>
__device__ void gemm_tile(const u16* __restrict__ A, const u16* __restrict__ Bt,
                          const float* __restrict__ bias, const float* __restrict__ alpha,
                          void* __restrict__ outp, int N, int K, int bn, int bmi,
                          u16* As, u16* Bs, int tid) {
    const int r0 = tid >> 3;           // 0..63 (+64 on second issue; (r&7) invariant)
    const int p  = tid & 7;
    const int c  = p ^ (r0 & 7);       // global k-chunk fetched into LDS pos p
    const u16* Ag = A  + (size_t)(bmi * 128 + r0) * K + c * 8;
    const u16* Bg = Bt + (size_t)(bn * 128 + r0) * K + c * 8;
    u16* Al = As + tid * 8;
    u16* Bl = Bs + tid * 8;

    const int lane = tid & 63, w = tid >> 6;
    const int wm = (w >> 2) * 64, wn = (w & 3) * 32;
    const int l16 = lane & 15, quad = lane >> 4;
    const int xr = l16 & 7;
    const short8* As8 = (const short8*)As;
    const short8* Bs8 = (const short8*)Bs;

    float4v acc[4][2] = {};

    const int nk = K >> 6;
    for (int kt = 0; kt < nk; ++kt) {
        gload16(Ag, Al);
        gload16(Ag + (size_t)64 * K, Al + 4096);
        gload16(Bg, Bl);
        gload16(Bg + (size_t)64 * K, Bl + 4096);
        __syncthreads();
        #pragma unroll
        for (int kk = 0; kk < 2; ++kk) {
            const int cb = kk * 4;
            short8 af[4], bf[2];
            #pragma unroll
            for (int mi = 0; mi < 4; ++mi)
                af[mi] = As8[(wm + mi * 16 + l16) * 8 + ((cb + quad) ^ xr)];
            #pragma unroll
            for (int ni = 0; ni < 2; ++ni)
                bf[ni] = Bs8[(wn + ni * 16 + l16) * 8 + ((cb + quad) ^ xr)];
            #pragma unroll
            for (int mi = 0; mi < 4; ++mi)
                #pragma unroll
                for (int ni = 0; ni < 2; ++ni)
                    acc[mi][ni] = __builtin_amdgcn_mfma_f32_16x16x32_bf16(
                        af[mi], bf[ni], acc[mi][ni], 0, 0, 0);
        }
        __syncthreads();
        Ag += 64; Bg += 64;
    }

    // epilogue: C/D layout col=lane&15, row=quad*4+reg  [m89/m91]
    const int cbase = bn * 128 + wn + l16;
    float bv[2], av[2];
    #pragma unroll
    for (int ni = 0; ni < 2; ++ni) { bv[ni] = bias[cbase + ni * 16]; av[ni] = alpha[cbase + ni * 16]; }
    const int rbase = bmi * 128 + wm + quad * 4;
    #pragma unroll
    for (int mi = 0; mi < 4; ++mi) {
        #pragma unroll
        for (int reg = 0; reg < 4; ++reg) {
            int r = rbase + mi * 16 + reg;
            #pragma unroll
            for (int ni = 0; ni < 2; ++ni) {
                float v = acc[mi][ni][reg] + bv[ni];
                v = v >= 0.f ? v : av[ni] * v;
                size_t idx = (size_t)r * N + cbase + ni * 16;
                if (OUT_F32) ((float*)outp)[idx] = v;
                else         ((u16*)outp)[idx] = f2bf(v);
            }
        }
    }
}

// ------------- fused whole-network kernel (cooperative) -------------
// 512 blocks x 512 thr = 2 blocks/CU (32 KB LDS each -> fits 64 KB/CU occupancy model).
__global__ __launch_bounds__(512, 4) void fused(Params p) {
    __shared__ __align__(16) u16 smem[2 * 128 * 64];   // 32 KB
    const int tid = threadIdx.x, bid = blockIdx.x;
    cg::grid_group grid = cg::this_grid();

    prep_phase(p, bid, tid, (float(*)[33])smem);
    __threadfence();
    grid.sync();

    u16* As = smem;
    u16* Bs = smem + 128 * 64;

    // L0: 8192x1024, K=512 — 8(bn) x 64(bmi) = 512 tiles, 1/block.
    // bmi = bid&63 -> blocks sharing an A-tile are bid≡bmi (mod 8): same XCD (L2 reuse).
    gemm_tile<false>(p.xbf, p.W0t, p.mb, p.a0, p.act1, 1024, 512, bid >> 6, bid & 63, As, Bs, tid);
    __threadfence();
    grid.sync();

    // L1: 8192x1024, K=1024 — 512 tiles
    gemm_tile<false>(p.act1, p.W1t, p.mb + 1024, p.a1, p.act2, 1024, 1024, bid >> 6, bid & 63, As, Bs, tid);
    __threadfence();
    grid.sync();

    // L2: 8192x512, K=1024 — 4 x 64 = 256 tiles
    if (bid < 256)
        gemm_tile<true>(p.act2, p.W2t, p.mb + 2048, p.a2, p.out, 512, 1024, bid >> 6, bid & 63, As, Bs, tid);
}

// ------------- fallback (non-cooperative) -------------
__global__ __launch_bounds__(512) void prep_k(Params p) {
    __shared__ float tile[32][33];
    prep_phase(p, blockIdx.x, threadIdx.x, tile);
}

template <bool OUT_F32>
__global__ __launch_bounds__(512, 4) void gemm_k(const u16* __restrict__ A, const u16* __restrict__ Bt,
                                                 const float* __restrict__ bias, const float* __restrict__ alpha,
                                                 void* __restrict__ outp, int N, int K) {
    __shared__ __align__(16) u16 smem[2 * 128 * 64];
    gemm_tile<OUT_F32>(A, Bt, bias, alpha, outp, N, K, blockIdx.x >> 6, blockIdx.x & 63,
                       smem, smem + 128 * 64, threadIdx.x);
}

extern "C" void kernel_launch(void* const* d_in, const int* in_sizes, int n_in,
                              void* d_out, int out_size, void* d_ws, size_t ws_size,
                              hipStream_t stream) {
    char* ws = (char*)d_ws;
    u16*   xbf  = (u16*)ws;  ws += (size_t)8192 * 512 * 2;
    u16*   act1 = (u16*)ws;  ws += (size_t)8192 * 1024 * 2;
    u16*   act2 = (u16*)ws;  ws += (size_t)8192 * 1024 * 2;
    u16*   W0t  = (u16*)ws;  ws += (size_t)1024 * 512 * 2;
    u16*   W1t  = (u16*)ws;  ws += (size_t)1024 * 1024 * 2;
    u16*   W2t  = (u16*)ws;  ws += (size_t)512 * 1024 * 2;
    float* mb   = (float*)ws;  // 2560 floats

    Params prm;
    prm.x   = (const float*)d_in[0];
    prm.wts = (const float*)d_in[1];
    prm.W0  = (const float*)d_in[2];
    prm.b0  = (const float*)d_in[3];
    prm.a0  = (const float*)d_in[4];
    prm.W1  = (const float*)d_in[5];
    prm.b1  = (const float*)d_in[6];
    prm.a1  = (const float*)d_in[7];
    prm.W2  = (const float*)d_in[8];
    prm.b2  = (const float*)d_in[9];
    prm.a2  = (const float*)d_in[10];
    prm.xbf = xbf; prm.act1 = act1; prm.act2 = act2;
    prm.W0t = W0t; prm.W1t = W1t; prm.W2t = W2t;
    prm.mb  = mb;
    prm.out = (float*)d_out;

    void* args[] = { (void*)&prm };
    hipError_t e = hipLaunchCooperativeKernel((const void*)fused, dim3(512), dim3(512),
                                              args, 0, stream);
    if (e != hipSuccess) {
        (void)hipGetLastError();   // clear sticky error, then same math via normal launches
        prep_k<<<512, 512, 0, stream>>>(prm);
        gemm_k<false><<<512, 512, 0, stream>>>(xbf,  W0t, mb,        prm.a0, act1, 1024, 512);
        gemm_k<false><<<512, 512, 0, stream>>>(act1, W1t, mb + 1024, prm.a1, act2, 1024, 1024);
        gemm_k<true ><<<256, 512, 0, stream>>>(act2, W2t, mb + 2048, prm.a2, prm.out, 512, 1024);
    }
}

// Round 5
// 196.752 us; speedup vs baseline: 3.6552x; 3.6552x over previous
//
#include <hip/hip_runtime.h>
#include <stdint.h>

typedef unsigned short u16;
typedef __attribute__((ext_vector_type(8))) short short8;   // 8 bf16 (4 VGPRs) — MFMA A/B frag
typedef __attribute__((ext_vector_type(4))) float float4v;  // MFMA C/D frag

__device__ __forceinline__ u16 f2bf(float f) {
    union { float f; uint32_t u; } v; v.f = f;
    uint32_t r = v.u + 0x7fffu + ((v.u >> 16) & 1u);  // RNE
    return (u16)(r >> 16);
}

__device__ __forceinline__ void gload16(const u16* g, u16* l) {
    __builtin_amdgcn_global_load_lds(
        (const __attribute__((address_space(1))) void*)g,
        (__attribute__((address_space(3))) void*)l, 16, 0, 0);
}

// ---------------- fused prep: x->bf16, 3x weight merge+transpose, bias merge ----
// block ranges: [0,4096) cvt | [4096,4608) W0 | [4608,5632) W1 | [5632,6144) W2
//               [6144,6154) bias     (proven in R2: passed, cheap)
__global__ __launch_bounds__(256) void prep_fused(
    const float* __restrict__ x, u16* __restrict__ xbf,
    const float* __restrict__ wts,
    const float* __restrict__ W0, const float* __restrict__ W1, const float* __restrict__ W2,
    u16* __restrict__ W0t, u16* __restrict__ W1t, u16* __restrict__ W2t,
    const float* __restrict__ b0, const float* __restrict__ b1, const float* __restrict__ b2,
    float* __restrict__ bm) {
    __shared__ float tile[32][33];
    const int b = blockIdx.x, tid = threadIdx.x;

    if (b < 4096) {                       // ---- x -> bf16, 4 elem/thread ----
        int i = (b * 256 + tid) * 4;
        float4 v = *(const float4*)(x + i);
        union { u16 s[4]; uint64_t q; } o;
        o.s[0] = f2bf(v.x); o.s[1] = f2bf(v.y); o.s[2] = f2bf(v.z); o.s[3] = f2bf(v.w);
        *(uint64_t*)(xbf + i) = o.q;
        return;
    }

    float wn[8]; float s = 0.f;
    #pragma unroll
    for (int e = 0; e < 8; ++e) { wn[e] = wts[e]; s += wn[e]; }
    const float inv = 1.0f / s;

    if (b < 6144) {                       // ---- weight merge + transpose ----
        const float* W; u16* Wt; int K, N, lb;
        if (b < 4608)      { W = W0; Wt = W0t; K = 512;  N = 1024; lb = b - 4096; }
        else if (b < 5632) { W = W1; Wt = W1t; K = 1024; N = 1024; lb = b - 4608; }
        else               { W = W2; Wt = W2t; K = 1024; N = 512;  lb = b - 5632; }
        const int ntiles = N >> 5;
        const int o0 = (lb % ntiles) * 32, i0 = (lb / ntiles) * 32;
        const int tx = tid & 31, ty = tid >> 5;
        #pragma unroll
        for (int s4 = 0; s4 < 4; ++s4) {
            int il = ty + s4 * 8;
            float acc = 0.f;
            #pragma unroll
            for (int e = 0; e < 8; ++e)
                acc += wn[e] * W[(size_t)e * K * N + (size_t)(i0 + il) * N + o0 + tx];
            tile[il][tx] = acc * inv;
        }
        __syncthreads();
        #pragma unroll
        for (int s4 = 0; s4 < 4; ++s4) {
            int ol = ty + s4 * 8;
            Wt[(size_t)(o0 + ol) * K + i0 + tx] = f2bf(tile[tx][ol]);
        }
        return;
    }

    // ---- bias merge: 2560 outputs ----
    int t = (b - 6144) * 256 + tid;
    if (t >= 2560) return;
    const float* bp; int o, stride;
    if (t < 1024)      { bp = b0; o = t;        stride = 1024; }
    else if (t < 2048) { bp = b1; o = t - 1024; stride = 1024; }
    else               { bp = b2; o = t - 2048; stride = 512;  }
    float acc = 0.f;
    #pragma unroll
    for (int e = 0; e < 8; ++e) acc += wn[e] * bp[e * stride + o];
    bm[t] = acc * inv;
}

// ------------- GEMM + bias + PReLU (R1-proven core + XCD-slab scheduling) -------------
// A [M,K] bf16 row-major, Bt [N,K] bf16 (B^T), out [M,N].
// 128x128 tile, BK=64, 256 thr = 4 waves in 2x2, each wave 64x64 = 4x4 MFMA 16x16x32.
// bid mapping: xcd = bid&7 owns an M-slab of 8 M-tiles (1024 rows). Per-XCD L2
// working set = A-slab (<=2 MB) + all of Bt (<=2 MB) <= 4 MiB L2 -> tile refetch
// becomes L2 hits instead of L3 (the R1-R2 limiter: staging at 43-64 f/B vs
// ~67 f/B needed at L2 BW; L3 BW made it memory-bound).
// NN_LOG2: log2(N/128) strips.
template <bool OUT_F32, int NN_LOG2>
__global__ __launch_bounds__(256) void gemm_bias_prelu(
    const u16* __restrict__ A, const u16* __restrict__ Bt,
    const float* __restrict__ bias, const float* __restrict__ alpha,
    void* __restrict__ outp, int M, int N, int K) {
    __shared__ __align__(16) u16 As[128 * 64];   // 16 KB
    __shared__ __align__(16) u16 Bs[128 * 64];   // 16 KB
    const int tid = threadIdx.x;

    const int xcd   = blockIdx.x & 7;
    const int inner = blockIdx.x >> 3;
    const int bn    = inner & ((1 << NN_LOG2) - 1);   // N-strip (fastest: consecutive share A-tile)
    const int bmv   = xcd * 8 + (inner >> NN_LOG2);   // M-tile within xcd's slab

    // staging: thread t, issue it -> LDS chunk (it*256 + t); row r = chunk/8, pos p = chunk%8
    const int r0 = tid >> 3;           // 0..31 (+32 per issue; (r&7) invariant)
    const int p  = tid & 7;
    const int c  = p ^ (r0 & 7);       // XOR swizzle on GLOBAL source (LDS stays lane-contiguous)
    const u16* Ag = A  + (size_t)(bmv * 128 + r0) * K + c * 8;
    const u16* Bg = Bt + (size_t)(bn * 128 + r0) * K + c * 8;
    u16* Al = As + tid * 8;
    u16* Bl = Bs + tid * 8;

    const int lane = tid & 63, w = tid >> 6;
    const int wm = (w >> 1) * 64, wn = (w & 1) * 64;
    const int l16 = lane & 15, quad = lane >> 4;
    const int xr = l16 & 7;            // (row&7) of every fragment row (offsets ≡ 0 mod 8)
    const short8* As8 = (const short8*)As;
    const short8* Bs8 = (const short8*)Bs;

    float4v acc[4][4] = {};

    const int nk = K >> 6;
    for (int kt = 0; kt < nk; ++kt) {
        #pragma unroll
        for (int it = 0; it < 4; ++it) {
            gload16(Ag + (size_t)(it * 32) * K, Al + it * 2048);
            gload16(Bg + (size_t)(it * 32) * K, Bl + it * 2048);
        }
        __syncthreads();   // drains vmcnt (global_load_lds complete)
        #pragma unroll
        for (int kk = 0; kk < 2; ++kk) {
            const int cb = kk * 4;
            short8 af[4], bf[4];
            #pragma unroll
            for (int mi = 0; mi < 4; ++mi)
                af[mi] = As8[(wm + mi * 16 + l16) * 8 + ((cb + quad) ^ xr)];
            #pragma unroll
            for (int ni = 0; ni < 4; ++ni)
                bf[ni] = Bs8[(wn + ni * 16 + l16) * 8 + ((cb + quad) ^ xr)];
            #pragma unroll
            for (int mi = 0; mi < 4; ++mi)
                #pragma unroll
                for (int ni = 0; ni < 4; ++ni)
                    acc[mi][ni] = __builtin_amdgcn_mfma_f32_16x16x32_bf16(
                        af[mi], bf[ni], acc[mi][ni], 0, 0, 0);
        }
        if (kt + 1 < nk) __syncthreads();
        Ag += 64; Bg += 64;
    }

    // epilogue: C/D layout col=lane&15, row=quad*4+reg  [m89/m91 verified; R1 passed]
    const int cbase = bn * 128 + wn + l16;
    float bv[4], av[4];
    #pragma unroll
    for (int ni = 0; ni < 4; ++ni) { bv[ni] = bias[cbase + ni * 16]; av[ni] = alpha[cbase + ni * 16]; }
    const int rbase = bmv * 128 + wm + quad * 4;
    #pragma unroll
    for (int mi = 0; mi < 4; ++mi) {
        #pragma unroll
        for (int reg = 0; reg < 4; ++reg) {
            int r = rbase + mi * 16 + reg;
            #pragma unroll
            for (int ni = 0; ni < 4; ++ni) {
                float v = acc[mi][ni][reg] + bv[ni];
                v = v >= 0.f ? v : av[ni] * v;
                size_t idx = (size_t)r * N + cbase + ni * 16;
                if (OUT_F32) ((float*)outp)[idx] = v;
                else         ((u16*)outp)[idx] = f2bf(v);
            }
        }
    }
}

extern "C" void kernel_launch(void* const* d_in, const int* in_sizes, int n_in,
                              void* d_out, int out_size, void* d_ws, size_t ws_size,
                              hipStream_t stream) {
    const float* x   = (const float*)d_in[0];
    const float* wts = (const float*)d_in[1];
    const float* W0  = (const float*)d_in[2];
    const float* b0  = (const float*)d_in[3];
    const float* a0  = (const float*)d_in[4];
    const float* W1  = (const float*)d_in[5];
    const float* b1  = (const float*)d_in[6];
    const float* a1  = (const float*)d_in[7];
    const float* W2  = (const float*)d_in[8];
    const float* b2  = (const float*)d_in[9];
    const float* a2  = (const float*)d_in[10];
    float* out = (float*)d_out;

    char* ws = (char*)d_ws;
    u16*   xbf  = (u16*)ws;  ws += (size_t)8192 * 512 * 2;
    u16*   act1 = (u16*)ws;  ws += (size_t)8192 * 1024 * 2;
    u16*   act2 = (u16*)ws;  ws += (size_t)8192 * 1024 * 2;
    u16*   W0t  = (u16*)ws;  ws += (size_t)1024 * 512 * 2;
    u16*   W1t  = (u16*)ws;  ws += (size_t)1024 * 1024 * 2;
    u16*   W2t  = (u16*)ws;  ws += (size_t)512 * 1024 * 2;
    float* bm   = (float*)ws;  // 2560 floats

    // single fused prep launch (R2-proven)
    prep_fused<<<6154, 256, 0, stream>>>(x, xbf, wts, W0, W1, W2, W0t, W1t, W2t,
                                         b0, b1, b2, bm);

    // GEMM layers: 1D grid, xcd = bid&7 -> M-slab; L0/L1: 8 strips x 64 M-tiles = 512 blocks;
    // L2: 4 strips -> 256 blocks.
    gemm_bias_prelu<false, 3><<<512, 256, 0, stream>>>(xbf,  W0t, bm,        a0, act1, 8192, 1024, 512);
    gemm_bias_prelu<false, 3><<<512, 256, 0, stream>>>(act1, W1t, bm + 1024, a1, act2, 8192, 1024, 1024);
    gemm_bias_prelu<true,  2><<<256, 256, 0, stream>>>(act2, W2t, bm + 2048, a2, out,  8192, 512, 1024);
}